// Round 13
// baseline (148.838 us; speedup 1.0000x reference)
//
#include <hip/hip_runtime.h>
#include <stdint.h>
#include <math.h>

// Problem constants
#define TT  1024
#define BBN 4
#define CCH 1024
#define HHN 16
#define DHD 64
#define MMR 4096   // T*B rows
#define N3  3072

typedef __attribute__((ext_vector_type(4))) float  f32x4;
typedef __attribute__((ext_vector_type(8))) short  s16x8;
typedef __attribute__((ext_vector_type(8))) __bf16 bf16x8;

static __device__ __forceinline__ f32x4 mfma16(s16x8 a, s16x8 b, f32x4 c) {
  return __builtin_amdgcn_mfma_f32_16x16x32_bf16(
      __builtin_bit_cast(bf16x8, a), __builtin_bit_cast(bf16x8, b), c, 0, 0, 0);
}

static __device__ __forceinline__ unsigned short f2bf(float f) {
  union { float f; unsigned int u; } v; v.f = f;
  unsigned int u = v.u;
  return (unsigned short)((u + 0x7FFFu + ((u >> 16) & 1u)) >> 16);
}

typedef const __attribute__((address_space(1))) void GVoid;
typedef __attribute__((address_space(3))) void LVoid;
static __device__ __forceinline__ void gll16(const void* g, void* l) {
  __builtin_amdgcn_global_load_lds((GVoid*)g, (LVoid*)l, 16, 0, 0);
}

#if __has_builtin(__builtin_amdgcn_exp2f)
#define EXP2F(x) __builtin_amdgcn_exp2f(x)
#else
#define EXP2F(x) exp2f(x)
#endif

// ---------------------------------------------------------------- fused convert
__global__ void cvt_all(const float* __restrict__ x, const float* __restrict__ wqkv,
                        const float* __restrict__ wproj, unsigned short* __restrict__ out) {
  int i = blockIdx.x * blockDim.x + threadIdx.x;   // 0 .. 2097151
  const float4* src;
  int off;
  if (i < 1048576)      { src = (const float4*)x;     off = 0; }
  else if (i < 1835008) { src = (const float4*)wqkv;  off = 1048576; }
  else                  { src = (const float4*)wproj; off = 1835008; }
  float4 f = src[i - off];
  ushort4 o;
  o.x = f2bf(f.x); o.y = f2bf(f.y); o.z = f2bf(f.z); o.w = f2bf(f.w);
  ((ushort4*)out)[i] = o;
}

// ---------------------------------------------------------------- GEMM (C = A * Bw^T + bias)
// r12 validated: counted-vmcnt half-buffer pipeline (BK=32 ping-pong), T2
// both-sides chunk swizzle. MODE 0 (BN=64): f32 out. MODE 1 (BN=128): QKV scatter.
template <int MODE, int BN>
__global__ __launch_bounds__(256, MODE == 0 ? 4 : 3) void gemm_bt(
    const unsigned short* __restrict__ A, const unsigned short* __restrict__ Bw,
    const float* __restrict__ bias, float* __restrict__ Cout,
    unsigned short* __restrict__ qb, unsigned short* __restrict__ kb,
    unsigned short* __restrict__ vtb, int M, int N, int K) {
  constexpr int NI = BN / 32;                  // per-wave N-tiles (4 or 2)
  constexpr int AH = 128 * 32;                 // shorts per A half-buffer
  constexpr int BH = BN * 32;                  // shorts per B half-buffer
  __shared__ __align__(16) unsigned short sMem[2 * AH + 2 * BH];
  unsigned short* sA0 = sMem;
  unsigned short* sB0 = sMem + 2 * AH;
  const int tid = threadIdx.x;
  const int l = tid & 63, w = tid >> 6;
  const int g = l >> 4, c = l & 15;
  const int wr = w >> 1, wc = w & 1;           // 2x2 waves
  // XCD-aware bijective swizzle (grid counts are %8==0)
  const int total = gridDim.x * gridDim.y;
  const int flat = blockIdx.y * gridDim.x + blockIdx.x;
  const int wg = (flat & 7) * (total >> 3) + (flat >> 3);
  const int bxs = wg % gridDim.x, bys = wg / gridDim.x;
  const int bm = bys * 128, bn = bxs * BN;

  // staging geometry: 256 threads cover 64 rows x 4 chunks (16B) per issue
  const int srow = w * 16 + (l >> 2);          // 0..63
  const int schG = (l & 3) ^ ((l >> 3) & 3);   // pre-swizzled global chunk
  const unsigned short* Agp = A + (size_t)(bm + srow) * K + schG * 8;
  const unsigned short* Bgp = Bw + (size_t)(bn + srow) * K + schG * 8;
  const int swzR = (c >> 1) & 3;               // read-side swizzle key

  f32x4 acc[4][NI] = {};

#define GSTAGE(s, h) do {                                                        \
    _Pragma("unroll")                                                            \
    for (int i_ = 0; i_ < 2; ++i_)                                               \
      gll16(Agp + (size_t)(i_ * 64) * K + (s) * 32,                              \
            sA0 + (h) * AH + i_ * 2048 + w * 512);                               \
    _Pragma("unroll")                                                            \
    for (int i_ = 0; i_ < BN / 64; ++i_)                                         \
      gll16(Bgp + (size_t)(i_ * 64) * K + (s) * 32,                              \
            sB0 + (h) * BH + i_ * 2048 + w * 512);                               \
  } while (0)

#define GWAITN do {                                                              \
    if constexpr (BN == 128) asm volatile("s_waitcnt vmcnt(4)" ::: "memory");    \
    else                     asm volatile("s_waitcnt vmcnt(3)" ::: "memory");    \
  } while (0)

  const int NS = K >> 5;                       // 32 sub-steps
  GSTAGE(0, 0);
  GSTAGE(1, 1);
  GWAITN;                                      // chunk 0 landed (chunk 1 in flight)
  __builtin_amdgcn_s_barrier();

#pragma unroll 1
  for (int s = 0;; ++s) {
    const int h = s & 1;
    s16x8 af[4], bfr[NI];
#pragma unroll
    for (int mi = 0; mi < 4; ++mi)
      af[mi] = *(const s16x8*)&sA0[h * AH + (wr * 64 + mi * 16 + c) * 32 + (g ^ swzR) * 8];
#pragma unroll
    for (int ni = 0; ni < NI; ++ni)
      bfr[ni] = *(const s16x8*)&sB0[h * BH + (wc * (BN / 2) + ni * 16 + c) * 32 + (g ^ swzR) * 8];
#pragma unroll
    for (int mi = 0; mi < 4; ++mi)
#pragma unroll
      for (int ni = 0; ni < NI; ++ni)
        acc[mi][ni] = mfma16(af[mi], bfr[ni], acc[mi][ni]);
    if (s == NS - 1) break;
    __builtin_amdgcn_s_barrier();              // all waves done reading half h
    if (s + 2 < NS) { GSTAGE(s + 2, h); GWAITN; }
    else            { asm volatile("s_waitcnt vmcnt(0)" ::: "memory"); }
    __builtin_amdgcn_s_barrier();              // chunk s+1 landed for all waves
  }

#undef GSTAGE
#undef GWAITN

  if (MODE == 1 && (bn >> 10) == 2) {
    // V-block epilogue: LDS transpose, coalesced vt stores
    unsigned short* sT = sMem;                 // 128 x 72 shorts = 18KB
    const int tl0 = bm >> 2;
#pragma unroll
    for (int pc = 0; pc < 2; ++pc) {
      __syncthreads();
      if (wc == pc) {
#pragma unroll
        for (int mi = 0; mi < 4; ++mi)
#pragma unroll
          for (int ni = 0; ni < NI; ++ni) {
            const int col = bn + pc * 64 + ni * 16 + c;
            const float bsv = bias[col];
#pragma unroll
            for (int j = 0; j < 4; ++j)
              sT[(wr * 64 + mi * 16 + g * 4 + j) * 72 + ni * 16 + c] =
                  f2bf(acc[mi][ni][j] + bsv);
          }
      }
      __syncthreads();
      const int h2 = ((bn + pc * 64) & 1023) >> 6;
      unsigned short* vdst = vtb + ((size_t)(w * 16 + h2) * 64 + l) * 1024 + tl0;
#pragma unroll
      for (int q8 = 0; q8 < 4; ++q8) {
        unsigned short pk[8];
#pragma unroll
        for (int e = 0; e < 8; ++e)
          pk[e] = sT[(((q8 * 8 + e) << 2) | w) * 72 + l];
        *(s16x8*)&vdst[q8 * 8] = *(const s16x8*)pk;
      }
    }
    return;
  }

#pragma unroll
  for (int mi = 0; mi < 4; ++mi)
#pragma unroll
    for (int ni = 0; ni < NI; ++ni) {
      const int col = bn + wc * (BN / 2) + ni * 16 + c;
      const float bsv = bias[col];
      if (MODE == 0) {
#pragma unroll
        for (int j = 0; j < 4; ++j) {
          const int r = bm + wr * 64 + mi * 16 + g * 4 + j;
          Cout[(size_t)r * N + col] = acc[mi][ni][j] + bsv;
        }
      } else {
        const int rem = col & 1023;
        const int h = rem >> 6, d = rem & 63;
        const bool isq = (col >> 10) == 0;
        const float qscale = 0.18033688f;      // SCALING * log2(e)
#pragma unroll
        for (int j = 0; j < 4; ++j) {
          const int r = bm + wr * 64 + mi * 16 + g * 4 + j;
          const int t = r >> 2, bb = r & 3;
          const int bh = bb * 16 + h;
          float av = acc[mi][ni][j] + bsv;
          if (isq) qb[((size_t)bh * 1024 + t) * 64 + d] = f2bf(av * qscale);
          else     kb[((size_t)bh * 1024 + t) * 64 + d] = f2bf(av);
        }
      }
    }
}

// ---------------------------------------------------------------- flash attention + edge bias
// KVBLK=32 LDS diet: sK/sV 2x4KB each (dbuf), no sQ (Q frags loaded directly
// from global: two 16B contiguous loads/thread), sP stride-40 strips (banks
// 2-way-free), mask 1KB -> 22KB total -> all 1024 blocks resident (4/CU) in
// ONE round (was 3/CU = 768+256 tail). r9's counted-vmcnt schedule re-derived:
// 10 loads/tile prefetch -> steady vmcnt(10), tail vmcnt(0). Accumulation
// order bit-identical to r9 (old kk=0/1 halves == new even/odd tiles).
__global__ __launch_bounds__(256, 4) void attn_kernel(
    const unsigned short* __restrict__ qb, const unsigned short* __restrict__ kb,
    const unsigned short* __restrict__ vtb, const float* __restrict__ eb,
    const unsigned char* __restrict__ mask, unsigned short* __restrict__ ob) {
  __shared__ __align__(16) unsigned short sK[2][32 * 64];   // [s][d], chunk-swz (row&7)
  __shared__ __align__(16) unsigned short sV[2][64 * 32];   // [d][s], chunk-swz ((row>>1)&3)
  __shared__ __align__(16) unsigned short sP[4][16 * 40];   // per-wave P strips
  __shared__ __align__(4) unsigned char sM[1024];
  const int tid = threadIdx.x;
  const int l = tid & 63, w = tid >> 6;
  const int g = l >> 4, c = l & 15;
  const int flat = blockIdx.y * 16 + blockIdx.x;
  const int wg = (flat & 7) * 128 + (flat >> 3);
  const int q0 = (wg & 15) * 64;
  const int bh = wg >> 4;
  const int b = bh >> 4;
  // staging lanes: K rows w*8+(l>>3) x 8 chunks; V rows w*16+(l>>2) x 4 chunks
  const int srK = w * 8 + (l >> 3), scK = l & 7;
  const int srV = w * 16 + (l >> 2), scV = l & 3;

  const unsigned short* qg = qb + (size_t)bh * 65536;
  const unsigned short* kg = kb + (size_t)bh * 65536;
  const unsigned short* vg = vtb + (size_t)bh * 65536;
  const float* ebg = eb + (size_t)bh * 1048576 + (size_t)(q0 + w * 16 + g * 4) * 1024;

  const float BS = 1.44269504f;
  float bvA[2][4], bvB[2][4];
  float ps[4] = {0.f, 0.f, 0.f, 0.f};
  f32x4 po[4] = {};

#define STAGE(tv, P) do {                                                        \
    gll16(kg + (size_t)((tv) * 32 + srK) * 64 + ((scK ^ (srK & 7)) * 8),         \
          &sK[P][w * 512]);                                                      \
    gll16(vg + (size_t)srV * 1024 + (tv) * 32 + ((scV ^ ((srV >> 1) & 3)) * 8),  \
          &sV[P][w * 512]);                                                      \
  } while (0)

#define BIAS(tv, BV) do {                                                        \
    _Pragma("unroll")                                                            \
    for (int ni_ = 0; ni_ < 2; ++ni_)                                            \
      _Pragma("unroll")                                                          \
      for (int j_ = 0; j_ < 4; ++j_)                                             \
        BV[ni_][j_] = ebg[(size_t)j_ * 1024 + (tv) * 32 + ni_ * 16 + c];         \
    } while (0)

#define TILE(P, BV, s0v) do {                                                    \
    float mkc_[2];                                                               \
    _Pragma("unroll")                                                            \
    for (int ni_ = 0; ni_ < 2; ++ni_)                                            \
      mkc_[ni_] = sM[(s0v) + ni_ * 16 + c] ? -1e30f : -8.0f;                     \
    s16x8 kf_[2][2];                                                             \
    _Pragma("unroll")                                                            \
    for (int ni_ = 0; ni_ < 2; ++ni_)                                            \
      _Pragma("unroll")                                                          \
      for (int k2_ = 0; k2_ < 2; ++k2_)                                          \
        kf_[ni_][k2_] = *(const s16x8*)&sK[P][(ni_ * 16 + c) * 64 +              \
                         (((k2_ * 4 + g) ^ (c & 7)) * 8)];                       \
    f32x4 sc_[2] = {};                                                           \
    _Pragma("unroll")                                                            \
    for (int k2_ = 0; k2_ < 2; ++k2_)                                            \
      _Pragma("unroll")                                                          \
      for (int ni_ = 0; ni_ < 2; ++ni_)                                          \
        sc_[ni_] = mfma16(qf[k2_], kf_[ni_][k2_], sc_[ni_]);                     \
    _Pragma("unroll")                                                            \
    for (int ni_ = 0; ni_ < 2; ++ni_)                                            \
      _Pragma("unroll")                                                          \
      for (int j_ = 0; j_ < 4; ++j_) {                                           \
        float x_ = fmaf(BV[ni_][j_], BS, sc_[ni_][j_]) + mkc_[ni_];              \
        float p_ = EXP2F(x_);                                                    \
        sP[w][(g * 4 + j_) * 40 + ni_ * 16 + c] = f2bf(p_);                      \
        ps[j_] += p_;                                                            \
      }                                                                          \
    s16x8 vf_[4];                                                                \
    _Pragma("unroll")                                                            \
    for (int nd_ = 0; nd_ < 4; ++nd_)                                            \
      vf_[nd_] = *(const s16x8*)&sV[P][(nd_ * 16 + c) * 32 +                     \
                  ((g ^ ((c >> 1) & 3)) * 8)];                                   \
    asm volatile("s_waitcnt lgkmcnt(0)" ::: "memory");                           \
    __builtin_amdgcn_sched_barrier(0);                                           \
    s16x8 pf_ = *(const s16x8*)&sP[w][c * 40 + g * 8];                           \
    _Pragma("unroll")                                                            \
    for (int nd_ = 0; nd_ < 4; ++nd_)                                            \
      po[nd_] = mfma16(pf_, vf_[nd_], po[nd_]);                                  \
  } while (0)

  // ---- prologue: Q frags direct from global; tiles 0,1; bias 0,1; mask; drain
  s16x8 qf[2];
#pragma unroll
  for (int kk2 = 0; kk2 < 2; ++kk2)
    qf[kk2] = *(const s16x8*)&qg[(size_t)(q0 + w * 16 + c) * 64 + kk2 * 32 + g * 8];
  STAGE(0, 0);
  STAGE(1, 1);
  BIAS(0, bvA);
  BIAS(1, bvB);
  ((unsigned int*)sM)[tid] = ((const unsigned int*)(mask + b * TT))[tid & 255];
  __syncthreads();

  // ---- pipelined main loop: 32 tiles, pairs (even->buf0/bvA, odd->buf1/bvB)
#pragma unroll 1
  for (int t2 = 0;; t2 += 2) {
    TILE(0, bvA, t2 * 32);
    __builtin_amdgcn_s_barrier();                 // all waves done reading buf0
    if (t2 + 2 < 32) {
      STAGE(t2 + 2, 0); BIAS(t2 + 2, bvA);
      asm volatile("s_waitcnt vmcnt(10)" ::: "memory");
    } else {
      asm volatile("s_waitcnt vmcnt(0)" ::: "memory");
    }
    __builtin_amdgcn_s_barrier();                 // stage(t2+1) landed for all
    TILE(1, bvB, t2 * 32 + 32);
    if (t2 == 30) break;
    __builtin_amdgcn_s_barrier();                 // all waves done reading buf1
    STAGE(t2 + 3, 1); BIAS(t2 + 3, bvB);
    asm volatile("s_waitcnt vmcnt(10)" ::: "memory");
    __builtin_amdgcn_s_barrier();                 // stage(t2+2) landed for all
  }

#undef STAGE
#undef BIAS
#undef TILE

  // ---- epilogue: denominator reduction + store
#pragma unroll
  for (int j = 0; j < 4; ++j) {
#pragma unroll
    for (int off = 1; off <= 8; off <<= 1)
      ps[j] += __shfl_xor(ps[j], off, 64);
    ps[j] = 1.0f / ps[j];
  }
  const int h = bh & 15;
#pragma unroll
  for (int nd = 0; nd < 4; ++nd)
#pragma unroll
    for (int j = 0; j < 4; ++j) {
      float val = po[nd][j] * ps[j];
      int t = q0 + w * 16 + g * 4 + j;
      ob[((size_t)t * 4 + b) * 1024 + h * 64 + nd * 16 + c] = f2bf(val);
    }
}

// ---------------------------------------------------------------- launch
extern "C" void kernel_launch(void* const* d_in, const int* in_sizes, int n_in,
                              void* d_out, int out_size, void* d_ws, size_t ws_size,
                              hipStream_t stream) {
  const float* x      = (const float*)d_in[0];
  const unsigned char* mask = (const unsigned char*)d_in[1];
  const float* ebias  = (const float*)d_in[2];
  const float* wqkv   = (const float*)d_in[3];
  const float* bqkv   = (const float*)d_in[4];
  const float* wproj  = (const float*)d_in[5];
  const float* bproj  = (const float*)d_in[6];
  float* out = (float*)d_out;

  char* ws = (char*)d_ws;
  unsigned short* xb    = (unsigned short*)(ws);              //  [4096][1024]
  unsigned short* wqkvb = (unsigned short*)(ws + 8388608);    //  [3072][1024]
  unsigned short* wpb   = (unsigned short*)(ws + 14680064);   //  [1024][1024]
  unsigned short* qbuf  = (unsigned short*)(ws + 16777216);   //  [bh][t][d]
  unsigned short* kbuf  = (unsigned short*)(ws + 25165824);   //  [bh][t][d]
  unsigned short* vtbuf = (unsigned short*)(ws + 33554432);   //  [bh][d][t]
  unsigned short* obuf  = (unsigned short*)(ws + 41943040);   //  [4096][1024]

  cvt_all<<<8192, 256, 0, stream>>>(x, wqkv, wproj, xb);

  gemm_bt<1, 128><<<dim3(24, 32), 256, 0, stream>>>(
      xb, wqkvb, bqkv, nullptr, qbuf, kbuf, vtbuf, MMR, N3, 1024);

  attn_kernel<<<dim3(16, 64), 256, 0, stream>>>(
      qbuf, kbuf, vtbuf, ebias, mask, obuf);

  gemm_bt<0, 64><<<dim3(16, 32), 256, 0, stream>>>(
      obuf, wpb, bproj, out, nullptr, nullptr, nullptr, MMR, 1024, 1024);
}

// Round 14
// 146.819 us; speedup vs baseline: 1.0138x; 1.0138x over previous
//
#include <hip/hip_runtime.h>
#include <stdint.h>
#include <math.h>

// Problem constants
#define TT  1024
#define BBN 4
#define CCH 1024
#define HHN 16
#define DHD 64
#define MMR 4096   // T*B rows
#define N3  3072

typedef __attribute__((ext_vector_type(4))) float  f32x4;
typedef __attribute__((ext_vector_type(8))) short  s16x8;
typedef __attribute__((ext_vector_type(8))) __bf16 bf16x8;

static __device__ __forceinline__ f32x4 mfma16(s16x8 a, s16x8 b, f32x4 c) {
  return __builtin_amdgcn_mfma_f32_16x16x32_bf16(
      __builtin_bit_cast(bf16x8, a), __builtin_bit_cast(bf16x8, b), c, 0, 0, 0);
}

static __device__ __forceinline__ unsigned short f2bf(float f) {
  union { float f; unsigned int u; } v; v.f = f;
  unsigned int u = v.u;
  return (unsigned short)((u + 0x7FFFu + ((u >> 16) & 1u)) >> 16);
}

typedef const __attribute__((address_space(1))) void GVoid;
typedef __attribute__((address_space(3))) void LVoid;
static __device__ __forceinline__ void gll16(const void* g, void* l) {
  __builtin_amdgcn_global_load_lds((GVoid*)g, (LVoid*)l, 16, 0, 0);
}

#if __has_builtin(__builtin_amdgcn_exp2f)
#define EXP2F(x) __builtin_amdgcn_exp2f(x)
#else
#define EXP2F(x) exp2f(x)
#endif

// ---------------------------------------------------------------- fused convert
__global__ void cvt_all(const float* __restrict__ x, const float* __restrict__ wqkv,
                        const float* __restrict__ wproj, unsigned short* __restrict__ out) {
  int i = blockIdx.x * blockDim.x + threadIdx.x;   // 0 .. 2097151
  const float4* src;
  int off;
  if (i < 1048576)      { src = (const float4*)x;     off = 0; }
  else if (i < 1835008) { src = (const float4*)wqkv;  off = 1048576; }
  else                  { src = (const float4*)wproj; off = 1835008; }
  float4 f = src[i - off];
  ushort4 o;
  o.x = f2bf(f.x); o.y = f2bf(f.y); o.z = f2bf(f.z); o.w = f2bf(f.w);
  ((ushort4*)out)[i] = o;
}

// ---------------------------------------------------------------- GEMM (C = A * Bw^T + bias)
// 3-deep chunk rotation: chunk s lives in buf s%3; stage(s+3) issued right
// after compute(s) -> issue-to-wait distance = 2 compute phases (~470 cyc),
// covering L2/L3 latency (r12's 1-deep covered only ~235). vmcnt ladder:
// steady 2-chunks-out, tail 1, last 0. T2 both-sides chunk swizzle kept.
// MODE 0 (BN=64): f32 out, 36KB LDS, 4 blk/CU. MODE 1 (BN=128): QKV, 48KB, 3.
template <int MODE, int BN>
__global__ __launch_bounds__(256, MODE == 0 ? 4 : 3) void gemm_bt(
    const unsigned short* __restrict__ A, const unsigned short* __restrict__ Bw,
    const float* __restrict__ bias, float* __restrict__ Cout,
    unsigned short* __restrict__ qb, unsigned short* __restrict__ kb,
    unsigned short* __restrict__ vtb, int M, int N, int K) {
  constexpr int NI = BN / 32;                  // per-wave N-tiles (4 or 2)
  constexpr int AH = 128 * 32;                 // shorts per A chunk-buffer
  constexpr int BH = BN * 32;                  // shorts per B chunk-buffer
  __shared__ __align__(16) unsigned short sMem[3 * AH + 3 * BH];
  unsigned short* sA0 = sMem;
  unsigned short* sB0 = sMem + 3 * AH;
  const int tid = threadIdx.x;
  const int l = tid & 63, w = tid >> 6;
  const int g = l >> 4, c = l & 15;
  const int wr = w >> 1, wc = w & 1;           // 2x2 waves
  // XCD-aware bijective swizzle (grid counts are %8==0)
  const int total = gridDim.x * gridDim.y;
  const int flat = blockIdx.y * gridDim.x + blockIdx.x;
  const int wg = (flat & 7) * (total >> 3) + (flat >> 3);
  const int bxs = wg % gridDim.x, bys = wg / gridDim.x;
  const int bm = bys * 128, bn = bxs * BN;

  // staging geometry: 256 threads cover 64 rows x 4 chunks (16B) per issue
  const int srow = w * 16 + (l >> 2);          // 0..63
  const int schG = (l & 3) ^ ((l >> 3) & 3);   // pre-swizzled global chunk
  const unsigned short* Agp = A + (size_t)(bm + srow) * K + schG * 8;
  const unsigned short* Bgp = Bw + (size_t)(bn + srow) * K + schG * 8;
  const int swzR = (c >> 1) & 3;               // read-side swizzle key

  f32x4 acc[4][NI] = {};

#define GSTAGE(s, h) do {                                                        \
    _Pragma("unroll")                                                            \
    for (int i_ = 0; i_ < 2; ++i_)                                               \
      gll16(Agp + (size_t)(i_ * 64) * K + (s) * 32,                              \
            sA0 + (h) * AH + i_ * 2048 + w * 512);                               \
    _Pragma("unroll")                                                            \
    for (int i_ = 0; i_ < BN / 64; ++i_)                                         \
      gll16(Bgp + (size_t)(i_ * 64) * K + (s) * 32,                              \
            sB0 + (h) * BH + i_ * 2048 + w * 512);                               \
  } while (0)

  // loads/thread/stage L = 2 + BN/64 (4 for BN=128, 3 for BN=64)
#define GWAIT2 do {                                                              \
    if constexpr (BN == 128) asm volatile("s_waitcnt vmcnt(8)" ::: "memory");    \
    else                     asm volatile("s_waitcnt vmcnt(6)" ::: "memory");    \
  } while (0)
#define GWAIT1 do {                                                              \
    if constexpr (BN == 128) asm volatile("s_waitcnt vmcnt(4)" ::: "memory");    \
    else                     asm volatile("s_waitcnt vmcnt(3)" ::: "memory");    \
  } while (0)

  const int NS = K >> 5;                       // 32 sub-steps
  GSTAGE(0, 0);
  GSTAGE(1, 1);
  GSTAGE(2, 2);
  GWAIT2;                                      // chunk 0 landed (1,2 in flight)
  __builtin_amdgcn_s_barrier();

  int h = 0;                                   // rotating buffer index (s % 3)
#pragma unroll 1
  for (int s = 0;; ++s) {
    s16x8 af[4], bfr[NI];
#pragma unroll
    for (int mi = 0; mi < 4; ++mi)
      af[mi] = *(const s16x8*)&sA0[h * AH + (wr * 64 + mi * 16 + c) * 32 + (g ^ swzR) * 8];
#pragma unroll
    for (int ni = 0; ni < NI; ++ni)
      bfr[ni] = *(const s16x8*)&sB0[h * BH + (wc * (BN / 2) + ni * 16 + c) * 32 + (g ^ swzR) * 8];
#pragma unroll
    for (int mi = 0; mi < 4; ++mi)
#pragma unroll
      for (int ni = 0; ni < NI; ++ni)
        acc[mi][ni] = mfma16(af[mi], bfr[ni], acc[mi][ni]);
    if (s == NS - 1) break;
    __builtin_amdgcn_s_barrier();              // all waves done reading buf h
    if (s + 3 < NS)      { GSTAGE(s + 3, h); GWAIT2; }  // chunk s+1 landed
    else if (s + 2 < NS) { GWAIT1; }                     // chunk s+1 landed
    else                 { asm volatile("s_waitcnt vmcnt(0)" ::: "memory"); }
    __builtin_amdgcn_s_barrier();              // landing visible to all waves
    h = (h == 2) ? 0 : h + 1;
  }

#undef GSTAGE
#undef GWAIT2
#undef GWAIT1

  if (MODE == 1 && (bn >> 10) == 2) {
    // V-block epilogue: LDS transpose, coalesced vt stores
    unsigned short* sT = sMem;                 // 128 x 72 shorts = 18KB
    const int tl0 = bm >> 2;
#pragma unroll
    for (int pc = 0; pc < 2; ++pc) {
      __syncthreads();
      if (wc == pc) {
#pragma unroll
        for (int mi = 0; mi < 4; ++mi)
#pragma unroll
          for (int ni = 0; ni < NI; ++ni) {
            const int col = bn + pc * 64 + ni * 16 + c;
            const float bsv = bias[col];
#pragma unroll
            for (int j = 0; j < 4; ++j)
              sT[(wr * 64 + mi * 16 + g * 4 + j) * 72 + ni * 16 + c] =
                  f2bf(acc[mi][ni][j] + bsv);
          }
      }
      __syncthreads();
      const int h2 = ((bn + pc * 64) & 1023) >> 6;
      unsigned short* vdst = vtb + ((size_t)(w * 16 + h2) * 64 + l) * 1024 + tl0;
#pragma unroll
      for (int q8 = 0; q8 < 4; ++q8) {
        unsigned short pk[8];
#pragma unroll
        for (int e = 0; e < 8; ++e)
          pk[e] = sT[(((q8 * 8 + e) << 2) | w) * 72 + l];
        *(s16x8*)&vdst[q8 * 8] = *(const s16x8*)pk;
      }
    }
    return;
  }

#pragma unroll
  for (int mi = 0; mi < 4; ++mi)
#pragma unroll
    for (int ni = 0; ni < NI; ++ni) {
      const int col = bn + wc * (BN / 2) + ni * 16 + c;
      const float bsv = bias[col];
      if (MODE == 0) {
#pragma unroll
        for (int j = 0; j < 4; ++j) {
          const int r = bm + wr * 64 + mi * 16 + g * 4 + j;
          Cout[(size_t)r * N + col] = acc[mi][ni][j] + bsv;
        }
      } else {
        const int rem = col & 1023;
        const int hh = rem >> 6, d = rem & 63;
        const bool isq = (col >> 10) == 0;
        const float qscale = 0.18033688f;      // SCALING * log2(e)
#pragma unroll
        for (int j = 0; j < 4; ++j) {
          const int r = bm + wr * 64 + mi * 16 + g * 4 + j;
          const int t = r >> 2, bb = r & 3;
          const int bh = bb * 16 + hh;
          float av = acc[mi][ni][j] + bsv;
          if (isq) qb[((size_t)bh * 1024 + t) * 64 + d] = f2bf(av * qscale);
          else     kb[((size_t)bh * 1024 + t) * 64 + d] = f2bf(av);
        }
      }
    }
}

// ---------------------------------------------------------------- flash attention + edge bias
// r12-exact (best known): counted-vmcnt pipeline, KVBLK=64, vmcnt(36/16).
__global__ __launch_bounds__(256, 3) void attn_kernel(
    const unsigned short* __restrict__ qb, const unsigned short* __restrict__ kb,
    const unsigned short* __restrict__ vtb, const float* __restrict__ eb,
    const unsigned char* __restrict__ mask, unsigned short* __restrict__ ob) {
  __shared__ __align__(16) unsigned short sQ[64 * 64];
  __shared__ __align__(16) unsigned short sK[2][64 * 64];
  __shared__ __align__(16) unsigned short sV[2][64 * 64];
  __shared__ __align__(16) unsigned short sP[4][16 * 72];
  __shared__ __align__(4) unsigned char sM[1024];
  const int tid = threadIdx.x;
  const int l = tid & 63, w = tid >> 6;
  const int g = l >> 4, c = l & 15;
  const int flat = blockIdx.y * 16 + blockIdx.x;
  const int wg = (flat & 7) * 128 + (flat >> 3);
  const int q0 = (wg & 15) * 64;
  const int bh = wg >> 4;
  const int b = bh >> 4;
  const int srow = tid >> 3, sch = tid & 7;

  const unsigned short* qg = qb + (size_t)bh * 65536;
  const unsigned short* kg = kb + (size_t)bh * 65536;
  const unsigned short* vg = vtb + (size_t)bh * 65536;
  const float* ebg = eb + (size_t)bh * 1048576 + (size_t)(q0 + w * 16 + g * 4) * 1024;

  const float BS = 1.44269504f;
  float bvA[4][4], bvB[4][4];
  float ps[4] = {0.f, 0.f, 0.f, 0.f};
  f32x4 po[4] = {};

#define STAGE(tv, P) do {                                                        \
    _Pragma("unroll")                                                            \
    for (int i_ = 0; i_ < 2; ++i_) {                                             \
      int row_ = i_ * 32 + srow;                                                 \
      gll16(kg + (size_t)((tv) * 64 + row_) * 64 + (sch ^ (row_ & 7)) * 8,       \
            &sK[P][i_ * 2048 + w * 512]);                                        \
      gll16(vg + (size_t)row_ * 1024 + (tv) * 64 + (sch ^ (row_ & 7)) * 8,       \
            &sV[P][i_ * 2048 + w * 512]);                                        \
    } } while (0)

#define BIAS(tv, BV) do {                                                        \
    _Pragma("unroll")                                                            \
    for (int ni_ = 0; ni_ < 4; ++ni_)                                            \
      _Pragma("unroll")                                                          \
      for (int j_ = 0; j_ < 4; ++j_)                                             \
        BV[ni_][j_] = ebg[(size_t)j_ * 1024 + (tv) * 64 + ni_ * 16 + c];         \
    } while (0)

#define TILE(P, BV, s0v) do {                                                    \
    float mkc_[4];                                                               \
    _Pragma("unroll")                                                            \
    for (int ni_ = 0; ni_ < 4; ++ni_)                                            \
      mkc_[ni_] = sM[(s0v) + ni_ * 16 + c] ? -1e30f : -8.0f;                     \
    s16x8 kf_[4][2];                                                             \
    _Pragma("unroll")                                                            \
    for (int ni_ = 0; ni_ < 4; ++ni_)                                            \
      _Pragma("unroll")                                                          \
      for (int k2_ = 0; k2_ < 2; ++k2_) {                                        \
        int row_ = ni_ * 16 + c;                                                 \
        kf_[ni_][k2_] = *(const s16x8*)&sK[P][row_ * 64 +                        \
                         (((k2_ * 4 + g) ^ (row_ & 7)) * 8)];                    \
      }                                                                          \
    f32x4 sc_[4] = {};                                                           \
    _Pragma("unroll")                                                            \
    for (int k2_ = 0; k2_ < 2; ++k2_)                                            \
      _Pragma("unroll")                                                          \
      for (int ni_ = 0; ni_ < 4; ++ni_)                                          \
        sc_[ni_] = mfma16(qf[k2_], kf_[ni_][k2_], sc_[ni_]);                     \
    _Pragma("unroll")                                                            \
    for (int ni_ = 0; ni_ < 4; ++ni_)                                            \
      _Pragma("unroll")                                                          \
      for (int j_ = 0; j_ < 4; ++j_) {                                           \
        float x_ = fmaf(BV[ni_][j_], BS, sc_[ni_][j_]) + mkc_[ni_];              \
        float p_ = EXP2F(x_);                                                    \
        sP[w][(g * 4 + j_) * 72 + ni_ * 16 + c] = f2bf(p_);                      \
        ps[j_] += p_;                                                            \
      }                                                                          \
    s16x8 vf_[4][2];                                                             \
    _Pragma("unroll")                                                            \
    for (int nd_ = 0; nd_ < 4; ++nd_)                                            \
      _Pragma("unroll")                                                          \
      for (int k2_ = 0; k2_ < 2; ++k2_) {                                        \
        int row_ = nd_ * 16 + c;                                                 \
        vf_[nd_][k2_] = *(const s16x8*)&sV[P][row_ * 64 +                        \
                         (((k2_ * 4 + g) ^ (row_ & 7)) * 8)];                    \
      }                                                                          \
    asm volatile("s_waitcnt lgkmcnt(0)" ::: "memory");                           \
    __builtin_amdgcn_sched_barrier(0);                                           \
    s16x8 pf_[2];                                                                \
    _Pragma("unroll")                                                            \
    for (int k2_ = 0; k2_ < 2; ++k2_)                                            \
      pf_[k2_] = *(const s16x8*)&sP[w][c * 72 + k2_ * 32 + g * 8];               \
    _Pragma("unroll")                                                            \
    for (int k2_ = 0; k2_ < 2; ++k2_)                                            \
      _Pragma("unroll")                                                          \
      for (int nd_ = 0; nd_ < 4; ++nd_)                                          \
        po[nd_] = mfma16(pf_[k2_], vf_[nd_][k2_], po[nd_]);                      \
  } while (0)

  // ---- prologue: Q + tiles 0,1 + bias 0,1 + mask->LDS; one full drain
#pragma unroll
  for (int i = 0; i < 2; ++i) {
    int row = i * 32 + srow;
    gll16(qg + (size_t)(q0 + row) * 64 + (sch ^ (row & 7)) * 8, &sQ[i * 2048 + w * 512]);
  }
  STAGE(0, 0);
  STAGE(1, 1);
  BIAS(0, bvA);
  BIAS(1, bvB);
  ((unsigned int*)sM)[tid] = ((const unsigned int*)(mask + b * TT))[tid & 255];
  __syncthreads();

  s16x8 qf[2];
#pragma unroll
  for (int kk2 = 0; kk2 < 2; ++kk2) {
    int row = w * 16 + c;
    qf[kk2] = *(const s16x8*)&sQ[row * 64 + (((kk2 * 4 + g) ^ (row & 7)) * 8)];
  }

  // ---- pipelined main loop (tiles paired: even->buf0/bvA, odd->buf1/bvB)
#pragma unroll 1
  for (int t2 = 0;; t2 += 2) {
    TILE(0, bvA, t2 * 64);
    __builtin_amdgcn_s_barrier();
    if (t2 + 2 < 16) { STAGE(t2 + 2, 0); BIAS(t2 + 2, bvA); }
    if (t2 == 14) { asm volatile("s_waitcnt vmcnt(16)" ::: "memory"); }
    else          { asm volatile("s_waitcnt vmcnt(36)" ::: "memory"); }
    __builtin_amdgcn_s_barrier();
    TILE(1, bvB, t2 * 64 + 64);
    if (t2 == 14) break;
    __builtin_amdgcn_s_barrier();
    STAGE(t2 + 3, 1); BIAS(t2 + 3, bvB);
    asm volatile("s_waitcnt vmcnt(36)" ::: "memory");
    __builtin_amdgcn_s_barrier();
  }

#undef STAGE
#undef BIAS
#undef TILE

  // ---- epilogue: denominator reduction + store
#pragma unroll
  for (int j = 0; j < 4; ++j) {
#pragma unroll
    for (int off = 1; off <= 8; off <<= 1)
      ps[j] += __shfl_xor(ps[j], off, 64);
    ps[j] = 1.0f / ps[j];
  }
  const int h = bh & 15;
#pragma unroll
  for (int nd = 0; nd < 4; ++nd)
#pragma unroll
    for (int j = 0; j < 4; ++j) {
      float val = po[nd][j] * ps[j];
      int t = q0 + w * 16 + g * 4 + j;
      ob[((size_t)t * 4 + b) * 1024 + h * 64 + nd * 16 + c] = f2bf(val);
    }
}

// ---------------------------------------------------------------- launch
extern "C" void kernel_launch(void* const* d_in, const int* in_sizes, int n_in,
                              void* d_out, int out_size, void* d_ws, size_t ws_size,
                              hipStream_t stream) {
  const float* x      = (const float*)d_in[0];
  const unsigned char* mask = (const unsigned char*)d_in[1];
  const float* ebias  = (const float*)d_in[2];
  const float* wqkv   = (const float*)d_in[3];
  const float* bqkv   = (const float*)d_in[4];
  const float* wproj  = (const float*)d_in[5];
  const float* bproj  = (const float*)d_in[6];
  float* out = (float*)d_out;

  char* ws = (char*)d_ws;
  unsigned short* xb    = (unsigned short*)(ws);              //  [4096][1024]
  unsigned short* wqkvb = (unsigned short*)(ws + 8388608);    //  [3072][1024]
  unsigned short* wpb   = (unsigned short*)(ws + 14680064);   //  [1024][1024]
  unsigned short* qbuf  = (unsigned short*)(ws + 16777216);   //  [bh][t][d]
  unsigned short* kbuf  = (unsigned short*)(ws + 25165824);   //  [bh][t][d]
  unsigned short* vtbuf = (unsigned short*)(ws + 33554432);   //  [bh][d][t]
  unsigned short* obuf  = (unsigned short*)(ws + 41943040);   //  [4096][1024]

  cvt_all<<<8192, 256, 0, stream>>>(x, wqkv, wproj, xb);

  gemm_bt<1, 128><<<dim3(24, 32), 256, 0, stream>>>(
      xb, wqkvb, bqkv, nullptr, qbuf, kbuf, vtbuf, MMR, N3, 1024);

  attn_kernel<<<dim3(16, 64), 256, 0, stream>>>(
      qbuf, kbuf, vtbuf, ebias, mask, obuf);

  gemm_bt<0, 64><<<dim3(16, 32), 256, 0, stream>>>(
      obuf, wpb, bproj, out, nullptr, nullptr, nullptr, MMR, 1024, 1024);
}